// Round 1
// baseline (504.367 us; speedup 1.0000x reference)
//
#include <hip/hip_runtime.h>

typedef __bf16 bf16x8 __attribute__((ext_vector_type(8)));
typedef float f32x4 __attribute__((ext_vector_type(4)));
typedef unsigned int u32;

// Problem constants: B=2 (derived at runtime), S=2048, D=1024, H=16, hd=64
#define QSCALE 0.18033688011112042f  // hd^-0.5 * log2(e), folded into Q

__device__ __forceinline__ void gld_lds16(const void* gsrc, void* ldst) {
  __builtin_amdgcn_global_load_lds(
      (const __attribute__((address_space(1))) u32*)gsrc,
      (__attribute__((address_space(3))) u32*)ldst, 16, 0, 0);
}

__device__ __forceinline__ float fexp2(float x) {
#if __has_builtin(__builtin_amdgcn_exp2f)
  return __builtin_amdgcn_exp2f(x);
#else
  return exp2f(x);
#endif
}

// ---------------- fp32 -> bf16 elementwise convert ----------------
__global__ __launch_bounds__(256) void cvt_f32_bf16(const float* __restrict__ src,
                                                    __bf16* __restrict__ dst, int n) {
  int i = (blockIdx.x * 256 + threadIdx.x) * 8;
  if (i >= n) return;
  const float4* p = (const float4*)(src + i);
  float4 a = p[0], b = p[1];
  bf16x8 v;
  v[0] = (__bf16)a.x; v[1] = (__bf16)a.y; v[2] = (__bf16)a.z; v[3] = (__bf16)a.w;
  v[4] = (__bf16)b.x; v[5] = (__bf16)b.y; v[6] = (__bf16)b.z; v[7] = (__bf16)b.w;
  *(bf16x8*)(dst + i) = v;
}

// ---------------- transpose fp32[R][C] -> bf16[C][R] (for B^T GEMM operands) ----------------
__global__ __launch_bounds__(256) void transpose_bf16(const float* __restrict__ src,
                                                      __bf16* __restrict__ dst, int R, int C) {
  __shared__ float tile[64 * 65];
  int c0 = blockIdx.x * 64, r0 = blockIdx.y * 64;
  int t = threadIdx.x;
  for (int i = 0; i < 16; ++i) {
    int idx = t + i * 256; int rr = idx >> 6, cc = idx & 63;
    tile[rr * 65 + cc] = src[(size_t)(r0 + rr) * C + (c0 + cc)];
  }
  __syncthreads();
  for (int i = 0; i < 16; ++i) {
    int idx = t + i * 256; int cc = idx >> 6, rr = idx & 63;
    dst[(size_t)(c0 + cc) * R + (r0 + rr)] = (__bf16)tile[rr * 65 + cc];
  }
}

// ---------------- 128x128-tile bf16 MFMA GEMM (m97 structure), A[M][K] @ Bt[N][K]^T ----------------
// EPI 0: projection epilogue -> scatter Q (scaled), K, V into [b][h][s][64] bf16
// EPI 1: final epilogue -> fp32 out[row][c] = acc + bias0[c]
template<int EPI>
__global__ __launch_bounds__(256) void gemm128(
    const __bf16* __restrict__ A, const __bf16* __restrict__ Bt,
    int M, int N, int K,
    const float* __restrict__ bias0, const float* __restrict__ bias1,
    float* __restrict__ outf,
    __bf16* __restrict__ Qo, __bf16* __restrict__ Ko, __bf16* __restrict__ Vo)
{
  __shared__ __bf16 As[128 * 32];
  __shared__ __bf16 Bs[128 * 32];
  const int m0 = blockIdx.x * 128, n0 = blockIdx.y * 128;
  const int t = threadIdx.x, lane = t & 63, wave = t >> 6;
  const int wr = wave >> 1, wc = wave & 1;
  const int g = lane >> 4, ci = lane & 15;
  f32x4 acc[4][4];
#pragma unroll
  for (int i = 0; i < 4; ++i)
#pragma unroll
    for (int j = 0; j < 4; ++j) acc[i][j] = (f32x4){0.f, 0.f, 0.f, 0.f};

  const char* Ab = (const char*)A;
  const char* Bb = (const char*)Bt;
  for (int k0 = 0; k0 < K; k0 += 32) {
#pragma unroll
    for (int i = 0; i < 2; ++i) {
      int o = wave * 2048 + i * 1024 + lane * 16;   // linear LDS byte offset
      int row = o >> 6, cb = o & 63;                // 64B per (row, 32 k-elems)
      gld_lds16(Ab + ((size_t)(m0 + row) * K + k0) * 2 + cb, (char*)As + o);
      gld_lds16(Bb + ((size_t)(n0 + row) * K + k0) * 2 + cb, (char*)Bs + o);
    }
    __syncthreads();
    bf16x8 af[4], bfr[4];
#pragma unroll
    for (int i = 0; i < 4; ++i)
      af[i] = *(const bf16x8*)((const char*)As + (wr * 64 + i * 16 + ci) * 64 + g * 16);
#pragma unroll
    for (int j = 0; j < 4; ++j)
      bfr[j] = *(const bf16x8*)((const char*)Bs + (wc * 64 + j * 16 + ci) * 64 + g * 16);
#pragma unroll
    for (int i = 0; i < 4; ++i)
#pragma unroll
      for (int j = 0; j < 4; ++j)
        acc[i][j] = __builtin_amdgcn_mfma_f32_16x16x32_bf16(af[i], bfr[j], acc[i][j], 0, 0, 0);
    __syncthreads();
  }
  // epilogue: C row = (lane>>4)*4 + r, col = lane&15 (verified m89 layout)
#pragma unroll
  for (int j = 0; j < 4; ++j) {
    int c = n0 + wc * 64 + j * 16 + ci;
    float bias;
    if (EPI == 0) bias = (c < 1024) ? bias0[c] : bias1[c - 1024];
    else          bias = bias0[c];
#pragma unroll
    for (int i = 0; i < 4; ++i) {
      int rbase = m0 + wr * 64 + i * 16 + g * 4;
#pragma unroll
      for (int r = 0; r < 4; ++r) {
        int row = rbase + r;
        float v = acc[i][j][r] + bias;
        if (EPI == 1) {
          outf[(size_t)row * 1024 + c] = v;
        } else {
          int b = row >> 11, n = row & 2047;
          if (c < 1024) {
            int h = c >> 6, d = c & 63;
            Qo[(((size_t)(b * 16 + h)) * 2048 + n) * 64 + d] = (__bf16)(v * QSCALE);
          } else if (c < 2048) {
            int c2 = c - 1024; int h = c2 >> 6, d = c2 & 63;
            Ko[(((size_t)(b * 16 + h)) * 2048 + n) * 64 + d] = (__bf16)v;
          } else {
            int c2 = c - 2048; int h = c2 >> 6, d = c2 & 63;
            Vo[(((size_t)(b * 16 + h)) * 2048 + n) * 64 + d] = (__bf16)v;
          }
        }
      }
    }
  }
}

// ---------------- fused attention: scores + softmax + weights write + PV ----------------
// Block = (b, 16-row n-tile, all 16 heads); wave = head. Two passes over m:
//   pass A: swapped QK^T (mfma(K,Q)) -> online row max/sum (exp2 domain)
//   pass B: recompute scores, w = exp2(s-max)*inv -> LDS stage -> PV MFMA + coalesced weights write
__global__ __launch_bounds__(1024) void attn_kernel(
    const __bf16* __restrict__ Q, const __bf16* __restrict__ K, const __bf16* __restrict__ V,
    float* __restrict__ Wout, __bf16* __restrict__ Obf)
{
  __shared__ float W2[32 * 272];   // [m:32][n:16 *17pad + h], off = m*272 + n*17 + h
  const int blk = blockIdx.x;
  const int b = blk >> 7;          // 128 n-tiles per batch (S/16)
  const int n0 = (blk & 127) * 16;
  const int h = threadIdx.x >> 6;
  const int lane = threadIdx.x & 63;
  const int g = lane >> 4, ci = lane & 15;
  const size_t bh = (size_t)(b * 16 + h);
  const __bf16* Qh = Q + bh * 2048 * 64;
  const __bf16* Kh = K + bh * 2048 * 64;
  const __bf16* Vh = V + bh * 2048 * 64;

  // Q B-frags (B[k=d][col=n]: lane holds n=lane&15, d=(lane>>4)*8+j), reused all tiles
  bf16x8 qf0 = *(const bf16x8*)(Qh + (size_t)(n0 + ci) * 64 + g * 8);
  bf16x8 qf1 = *(const bf16x8*)(Qh + (size_t)(n0 + ci) * 64 + 32 + g * 8);

  // ---- pass A: row max & sum (each lane owns row n = lane&15; 8 vals/lane/tile) ----
  float runmax = -3.0e30f, runsum = 0.f;
  for (int m0 = 0; m0 < 2048; m0 += 32) {
    f32x4 st[2];
    st[0] = (f32x4){0.f,0.f,0.f,0.f}; st[1] = (f32x4){0.f,0.f,0.f,0.f};
#pragma unroll
    for (int fm = 0; fm < 2; ++fm) {
      const __bf16* kp = Kh + (size_t)(m0 + fm * 16 + ci) * 64;
      bf16x8 a0 = *(const bf16x8*)(kp + g * 8);
      bf16x8 a1 = *(const bf16x8*)(kp + 32 + g * 8);
      st[fm] = __builtin_amdgcn_mfma_f32_16x16x32_bf16(a0, qf0, st[fm], 0, 0, 0);
      st[fm] = __builtin_amdgcn_mfma_f32_16x16x32_bf16(a1, qf1, st[fm], 0, 0, 0);
    }
    float tmax = fmaxf(
        fmaxf(fmaxf(st[0][0], st[0][1]), fmaxf(st[0][2], st[0][3])),
        fmaxf(fmaxf(st[1][0], st[1][1]), fmaxf(st[1][2], st[1][3])));
    tmax = fmaxf(tmax, __shfl_xor(tmax, 16, 64));
    tmax = fmaxf(tmax, __shfl_xor(tmax, 32, 64));
    float nm = fmaxf(runmax, tmax);
    float tsum = 0.f;
#pragma unroll
    for (int fm = 0; fm < 2; ++fm)
#pragma unroll
      for (int r = 0; r < 4; ++r) tsum += fexp2(st[fm][r] - nm);
    tsum += __shfl_xor(tsum, 16, 64);
    tsum += __shfl_xor(tsum, 32, 64);
    runsum = runsum * fexp2(runmax - nm) + tsum;
    runmax = nm;
  }
  const float inv = 1.0f / runsum;

  // ---- pass B ----
  f32x4 oacc[4];
#pragma unroll
  for (int fd = 0; fd < 4; ++fd) oacc[fd] = (f32x4){0.f,0.f,0.f,0.f};

  for (int m0 = 0; m0 < 2048; m0 += 32) {
    // V B-frags: B[k=m][col=d]: lane needs V[m0+g*8+j][fd*16+ci] (L2-hot scalar gathers)
    bf16x8 vf[4];
#pragma unroll
    for (int fd = 0; fd < 4; ++fd) {
#pragma unroll
      for (int j = 0; j < 8; ++j)
        vf[fd][j] = Vh[(size_t)(m0 + g * 8 + j) * 64 + fd * 16 + ci];
    }
    // recompute scores
    f32x4 st[2];
    st[0] = (f32x4){0.f,0.f,0.f,0.f}; st[1] = (f32x4){0.f,0.f,0.f,0.f};
#pragma unroll
    for (int fm = 0; fm < 2; ++fm) {
      const __bf16* kp = Kh + (size_t)(m0 + fm * 16 + ci) * 64;
      bf16x8 a0 = *(const bf16x8*)(kp + g * 8);
      bf16x8 a1 = *(const bf16x8*)(kp + 32 + g * 8);
      st[fm] = __builtin_amdgcn_mfma_f32_16x16x32_bf16(a0, qf0, st[fm], 0, 0, 0);
      st[fm] = __builtin_amdgcn_mfma_f32_16x16x32_bf16(a1, qf1, st[fm], 0, 0, 0);
    }
    // normalized weights -> LDS (fp32, doubles as PV A-source and output staging)
#pragma unroll
    for (int fm = 0; fm < 2; ++fm)
#pragma unroll
      for (int r = 0; r < 4; ++r) {
        float w = fexp2(st[fm][r] - runmax) * inv;
        int m = fm * 16 + g * 4 + r;
        W2[m * 272 + ci * 17 + h] = w;
      }
    // PV A-frag: A[row=n=ci][k=m=g*8+j] from own head's W2 slice (same-wave LDS, no barrier)
    bf16x8 wf;
#pragma unroll
    for (int j = 0; j < 8; ++j)
      wf[j] = (__bf16)W2[(g * 8 + j) * 272 + ci * 17 + h];
#pragma unroll
    for (int fd = 0; fd < 4; ++fd)
      oacc[fd] = __builtin_amdgcn_mfma_f32_16x16x32_bf16(wf, vf[fd], oacc[fd], 0, 0, 0);

    __syncthreads();
    // cooperative coalesced weights write: [n][m][h] contiguous 2KB runs
    size_t wbase = ((size_t)(b * 2048 + n0) * 2048 + m0) * 16;
#pragma unroll
    for (int it = 0; it < 8; ++it) {
      int idx = threadIdx.x + it * 1024;
      int n = idx >> 9, m = (idx >> 4) & 31, hh = idx & 15;
      Wout[wbase + ((size_t)n * 2048 + m) * 16 + hh] = W2[m * 272 + n * 17 + hh];
    }
    __syncthreads();
  }
  // O epilogue: C row = n = g*4+r, col = d = fd*16+ci -> Obf[b*S+n0+n][h*64+d]
#pragma unroll
  for (int fd = 0; fd < 4; ++fd)
#pragma unroll
    for (int r = 0; r < 4; ++r) {
      int n = g * 4 + r, d = fd * 16 + ci;
      Obf[((size_t)(b * 2048 + n0 + n)) * 1024 + h * 64 + d] = (__bf16)oacc[fd][r];
    }
}

extern "C" void kernel_launch(void* const* d_in, const int* in_sizes, int n_in,
                              void* d_out, int out_size, void* d_ws, size_t ws_size,
                              hipStream_t stream) {
  const float* queries = (const float*)d_in[0];
  const float* Wq  = (const float*)d_in[1];
  const float* bq  = (const float*)d_in[2];
  const float* Wkv = (const float*)d_in[3];
  const float* bkv = (const float*)d_in[4];
  const float* Wo  = (const float*)d_in[5];
  const float* bo  = (const float*)d_in[6];
  const int Bsz = in_sizes[0] / (2048 * 1024);
  const int M = Bsz * 2048;

  // workspace layout (bf16): Xbf | WcatT(3072x1024) | WoT(1024x1024) | Q | K | V | O
  size_t need = ((size_t)M * 1024 * 5 + (size_t)3072 * 1024 + (size_t)1024 * 1024) * 2;
  if (ws_size < need) return;  // insufficient scratch: fail loudly via validation

  __bf16* Xbf   = (__bf16*)d_ws;
  __bf16* WcatT = Xbf + (size_t)M * 1024;
  __bf16* WoT   = WcatT + (size_t)3072 * 1024;
  __bf16* Qb    = WoT + (size_t)1024 * 1024;
  __bf16* Kb    = Qb + (size_t)M * 1024;
  __bf16* Vb    = Kb + (size_t)M * 1024;
  __bf16* Ob    = Vb + (size_t)M * 1024;

  float* outp = (float*)d_out;
  float* wout = outp + (size_t)M * 1024;

  cvt_f32_bf16<<<(M * 1024) / (256 * 8), 256, 0, stream>>>(queries, Xbf, M * 1024);
  transpose_bf16<<<dim3(16, 16), 256, 0, stream>>>(Wq, WcatT, 1024, 1024);
  transpose_bf16<<<dim3(32, 16), 256, 0, stream>>>(Wkv, WcatT + (size_t)1024 * 1024, 1024, 2048);
  transpose_bf16<<<dim3(16, 16), 256, 0, stream>>>(Wo, WoT, 1024, 1024);
  gemm128<0><<<dim3(M / 128, 3072 / 128), 256, 0, stream>>>(
      Xbf, WcatT, M, 3072, 1024, bq, bkv, nullptr, Qb, Kb, Vb);
  attn_kernel<<<Bsz * 128, 1024, 0, stream>>>(Qb, Kb, Vb, wout, Ob);
  gemm128<1><<<dim3(M / 128, 1024 / 128), 256, 0, stream>>>(
      Ob, WoT, M, 1024, 1024, bo, nullptr, outp, nullptr, nullptr, nullptr);
}